// Round 13
// baseline (1829.086 us; speedup 1.0000x reference)
//
#include <hip/hip_runtime.h>
#include <hip/hip_fp16.h>

#define B_  16
#define T_  400
#define F_  512
#define U_  1024
#define G4_ 4096
#define NBLK 256

typedef __attribute__((ext_vector_type(8))) short short8;
typedef __attribute__((ext_vector_type(4))) float f32x4;

__device__ __forceinline__ unsigned bf16bits(float f) {
  unsigned u = __float_as_uint(f);
  return (u + 0x7fffu + ((u >> 16) & 1u)) >> 16;   // RNE f32->bf16
}
__device__ __forceinline__ float sigm(float x)   { return 1.f/(1.f + __expf(-x)); }
__device__ __forceinline__ float tanh_f(float x) { return 2.f/(1.f + __expf(-2.f*x)) - 1.f; }

__device__ __forceinline__ void ast(unsigned* p, unsigned v) {
  __hip_atomic_store(p, v, __ATOMIC_RELAXED, __HIP_MEMORY_SCOPE_AGENT);
}
// coherent 16B load (bypass L1/L2 -> coherence point); caller must waitcnt.
__device__ __forceinline__ uint4 ald4(const unsigned* p) {
  uint4 v;
  asm volatile("global_load_dwordx4 %0, %1, off sc0 sc1" : "=v"(v) : "v"(p));
  return v;
}

// ---------------- Phase 1: xw[dir] = x @ k_dir + b_dir (MFMA bf16) -------
// 128x128 tile / WG of 256 (4 waves as 2x2 of 64x64), K-step 32, bf16 LDS.
// Halves L3 tile re-read traffic vs the old 64x64 (the gemm was L3-BW bound).
__global__ __launch_bounds__(256) void gemm_xw(
    const float* __restrict__ X,
    const float* __restrict__ Kf, const float* __restrict__ Kb,
    const float* __restrict__ Bf, const float* __restrict__ Bb,
    __half* __restrict__ xwf, __half* __restrict__ xwb)
{
  const int dir = blockIdx.z;
  const float* Km   = dir ? Kb : Kf;
  const float* bias = dir ? Bb : Bf;
  __half* outp      = dir ? xwb : xwf;
  const int m0 = blockIdx.x * 128;
  const int n0 = blockIdx.y * 128;
  const int tid = threadIdx.x, wid = tid >> 6, lane = tid & 63;

  __shared__ unsigned short A_s[128*40];   // [m][k] bf16, row pad 40
  __shared__ unsigned short B_s[128*40];   // [n][k] bf16

  const int wm = wid >> 1, wn = wid & 1;   // wave -> 64x64 quadrant
  const int arow = lane & 15, kgrp = lane >> 4;

  f32x4 acc[4][4];
  #pragma unroll
  for (int i = 0; i < 4; ++i)
    #pragma unroll
    for (int j = 0; j < 4; ++j)
      acc[i][j] = (f32x4){0.f,0.f,0.f,0.f};

  for (int k0 = 0; k0 < F_; k0 += 32) {
    // A: 128x32 floats -> bf16 LDS [m][k]
    #pragma unroll
    for (int i = 0; i < 4; ++i) {
      const int idx = i*256 + tid;
      const int m = idx >> 3, kq = (idx & 7)*4;
      const float4 v = *reinterpret_cast<const float4*>(&X[(size_t)(m0+m)*F_ + k0 + kq]);
      unsigned short* d = &A_s[m*40 + kq];
      d[0]=(unsigned short)bf16bits(v.x); d[1]=(unsigned short)bf16bits(v.y);
      d[2]=(unsigned short)bf16bits(v.z); d[3]=(unsigned short)bf16bits(v.w);
    }
    // B: 32x128 floats -> bf16 LDS transposed [n][k]
    #pragma unroll
    for (int i = 0; i < 4; ++i) {
      const int idx = i*256 + tid;
      const int row = idx >> 5, c4 = (idx & 31)*4;
      const float4 v = *reinterpret_cast<const float4*>(&Km[(size_t)(k0+row)*G4_ + n0 + c4]);
      B_s[(c4+0)*40 + row] = (unsigned short)bf16bits(v.x);
      B_s[(c4+1)*40 + row] = (unsigned short)bf16bits(v.y);
      B_s[(c4+2)*40 + row] = (unsigned short)bf16bits(v.z);
      B_s[(c4+3)*40 + row] = (unsigned short)bf16bits(v.w);
    }
    __syncthreads();
    short8 af[4], bf4[4];
    #pragma unroll
    for (int t = 0; t < 4; ++t) {
      af[t]  = *reinterpret_cast<const short8*>(&A_s[(wm*64 + t*16 + arow)*40 + kgrp*8]);
      bf4[t] = *reinterpret_cast<const short8*>(&B_s[(wn*64 + t*16 + arow)*40 + kgrp*8]);
    }
    #pragma unroll
    for (int mt = 0; mt < 4; ++mt)
      #pragma unroll
      for (int nt = 0; nt < 4; ++nt)
        acc[mt][nt] = __builtin_amdgcn_mfma_f32_16x16x32_bf16(af[mt], bf4[nt], acc[mt][nt], 0, 0, 0);
    __syncthreads();
  }
  // epilogue: D row = kgrp*4+r (m), col = arow (n)  [validated mapping]
  #pragma unroll
  for (int mt = 0; mt < 4; ++mt) {
    #pragma unroll
    for (int nt = 0; nt < 4; ++nt) {
      const int n = n0 + wn*64 + nt*16 + arow;
      const float bv = bias[n];
      #pragma unroll
      for (int r = 0; r < 4; ++r) {
        const int m = m0 + wm*64 + mt*16 + kgrp*4 + r;
        outp[(size_t)m*G4_ + n] = __float2half_rn(acc[mt][nt][r] + bv);
      }
    }
  }
}

// ---------------- Phase 2: persistent bidirectional LSTM (MFMA) ----------
// EXACT round-11 kernel (proven). h exchange: PACKED dwords hw2p[par][dir]
// [16][512]: low16=bf16(h_even_u), high16=bf16(h_odd_u); TAG = bit0,
// expected bit at step s = ((s>>1)&1)^1. Buffer memset-0 each launch.
// Acquire = wait-until-fresh ONLY (sample spin, then full tag-validated
// load) — r12 showed accept-first-observation speculation is unsound here.
__global__ __launch_bounds__(256, 1) void lstm_rec(
    const __half* __restrict__ xwf, const __half* __restrict__ xwb,
    const float* __restrict__ Rf, const float* __restrict__ Rb,
    const float* __restrict__ gammav, const float* __restrict__ betav,
    const float* __restrict__ mmean, const float* __restrict__ mvar,
    unsigned* __restrict__ hw2p,    // [par2][dir2][16][512] packed dwords
    float* __restrict__ outp)       // [16][400][2048] f32
{
  __shared__ unsigned short r_bf[32*1040];     // 66560 B  [c][k] bf16
  __shared__ float z_s[2][4*528];              // 16896 B  [par][wave][16][33]
  // total 83456 B > 80K -> guaranteed 1 WG/CU

  const int wg  = blockIdx.x;
  const int dir = wg >> 7;
  const int u0  = (wg & 127) * 8;
  const __half* xw = dir ? xwb : xwf;
  const float*  R  = dir ? Rb  : Rf;
  const int tid  = threadIdx.x;
  const int wid  = tid >> 6;
  const int lane = tid & 63;

  // stage recurrent weights transposed: r_bf[c][k] = bf16(R[k][gc(c)])
  {
    const int c4 = (tid & 7) * 4;
    const int kb = (tid >> 3) * 32;
    const int gcol = ((c4 >> 3) * U_) + u0 + (c4 & 7);
    for (int kk = 0; kk < 32; ++kk) {
      const float4 rv = *reinterpret_cast<const float4*>(&R[(size_t)(kb+kk)*G4_ + gcol]);
      r_bf[(c4+0)*1040 + kb+kk] = (unsigned short)bf16bits(rv.x);
      r_bf[(c4+1)*1040 + kb+kk] = (unsigned short)bf16bits(rv.y);
      r_bf[(c4+2)*1040 + kb+kk] = (unsigned short)bf16bits(rv.z);
      r_bf[(c4+3)*1040 + kb+kk] = (unsigned short)bf16bits(rv.w);
    }
  }

  float inv = 0.f, add = 0.f, cst = 0.f;
  const int gb = tid >> 3, uu = tid & 7;       // reduce-thread mapping (tid<128)
  if (tid < 128) {
    const int j = dir*U_ + u0 + uu;
    inv = gammav[j] * rsqrtf(mvar[j] + 1e-3f);
    add = betav[j] - mmean[j]*inv;
    // h(0)=0 packed, parity 0, tag bit n=0 -> ((0>>1)&1)^1 = 1
    if (!(uu & 1))
      ast(&hw2p[(size_t)((0*2 + dir)*16 + gb)*512 + (u0 >> 1) + (uu >> 1)], 1u);
  }
  __syncthreads();                             // r_bf staged

  // MFMA fragment addressing + B-fragment preload (registers, loop-invariant)
  const int arow = lane & 15;                  // batch
  const int kgrp = lane >> 4;
  const unsigned short* bc0 = &r_bf[arow*1040 + wid*256];
  const unsigned short* bc1 = &r_bf[(16 + arow)*1040 + wid*256];
  #define LB(P, K) (*reinterpret_cast<const short8*>(&(P)[(K)*32 + kgrp*8]))
  const short8 rb00 = LB(bc0,0), rb01 = LB(bc0,1), rb02 = LB(bc0,2), rb03 = LB(bc0,3);
  const short8 rb04 = LB(bc0,4), rb05 = LB(bc0,5), rb06 = LB(bc0,6), rb07 = LB(bc0,7);
  const short8 rb10 = LB(bc1,0), rb11 = LB(bc1,1), rb12 = LB(bc1,2), rb13 = LB(bc1,3);
  const short8 rb14 = LB(bc1,4), rb15 = LB(bc1,5), rb16 = LB(bc1,6), rb17 = LB(bc1,7);
  #undef LB
  // packed layout: batch row stride 512 dwords; lane's k-chunk ks covers
  // dwords (wid*128 + kgrp*4 + ks*16 .. +4)  (8 k-values = 1 dwordx4)
  const size_t hfrag_off = (size_t)arow*512 + wid*128 + kgrp*4;
  // sample: u-block (lane&31) of this wave's quarter, batch (lane>>5)*8
  const size_t samp_off  = (size_t)((lane >> 5)*8)*512 + wid*128 + (lane & 31)*4;

  for (int s = 0; s < T_; ++s) {
    const int tin = dir ? (T_-1-s) : s;

    // xw prefetch (plain cached loads, issued pre-poll)
    float xv0=0.f, xv1=0.f, xv2=0.f, xv3=0.f;
    if (tid < 128) {
      const __half* xp = &xw[((size_t)gb*T_ + tin)*G4_ + u0 + uu];
      xv0 = __half2float(xp[0]);    xv1 = __half2float(xp[1024]);
      xv2 = __half2float(xp[2048]); xv3 = __half2float(xp[3072]);
    }

    const unsigned eb = (((unsigned)s >> 1) & 1u) ^ 1u;   // expected tag bit
    const size_t pbase = (size_t)((s&1)*2 + dir)*8192;
    #define CKB(Q) (((Q.x ^ eb) | (Q.y ^ eb) | (Q.z ^ eb) | (Q.w ^ eb)) & 1u)

    // cheap sample poll: one dwordx4 per lane, all 32 quarter-producers covered
    {
      const unsigned* sp = hw2p + pbase + samp_off;
      for (;;) {
        const uint4 t = ald4(sp);
        asm volatile("s_waitcnt vmcnt(0)" ::: "memory");
        if (__all((int)(CKB(t) == 0u))) break;
        __builtin_amdgcn_s_sleep(1);
      }
    }

    // full fragment load (8 x dwordx4 = 128B/lane), tag-validated
    const unsigned* hgp = hw2p + pbase + hfrag_off;
    uint4 q0,q1,q2,q3,q4,q5,q6,q7;
    for (;;) {
      q0 = ald4(hgp +  0); q1 = ald4(hgp + 16);
      q2 = ald4(hgp + 32); q3 = ald4(hgp + 48);
      q4 = ald4(hgp + 64); q5 = ald4(hgp + 80);
      q6 = ald4(hgp + 96); q7 = ald4(hgp + 112);
      asm volatile("s_waitcnt vmcnt(0)" ::: "memory");
      const unsigned mism = CKB(q0)|CKB(q1)|CKB(q2)|CKB(q3)
                          | CKB(q4)|CKB(q5)|CKB(q6)|CKB(q7);
      if (__all((int)(mism == 0u))) break;
      __builtin_amdgcn_s_sleep(1);
    }
    #undef CKB
    __builtin_amdgcn_sched_barrier(0);

    // MFMA: loaded uint4 IS the bf16x8 A-fragment (packed pairs in k-order)
    f32x4 acc0 = {0.f,0.f,0.f,0.f}, acc1 = {0.f,0.f,0.f,0.f};
    #define FRAG(Q, RB0, RB1) { \
      const short8 a = *reinterpret_cast<const short8*>(&Q); \
      acc0 = __builtin_amdgcn_mfma_f32_16x16x32_bf16(a, RB0, acc0, 0, 0, 0); \
      acc1 = __builtin_amdgcn_mfma_f32_16x16x32_bf16(a, RB1, acc1, 0, 0, 0); }
    FRAG(q0, rb00, rb10) FRAG(q1, rb01, rb11)
    FRAG(q2, rb02, rb12) FRAG(q3, rb03, rb13)
    FRAG(q4, rb04, rb14) FRAG(q5, rb05, rb15)
    FRAG(q6, rb06, rb16) FRAG(q7, rb07, rb17)
    #undef FRAG

    // z partials: D col=lane&15 (gate-col), row=kgrp*4+reg (batch)
    {
      const int col = lane & 15, rbase = kgrp*4;
      float* zw = &z_s[s&1][wid*528];
      #pragma unroll
      for (int r = 0; r < 4; ++r) {
        zw[(rbase+r)*33 + col]      = acc0[r];
        zw[(rbase+r)*33 + 16 + col] = acc1[r];
      }
    }
    __syncthreads();                           // all 4 waves' z(s) complete

    // reduce + gates + packed tagged h store (fire-and-forget) + outp
    if (tid < 128) {
      float zi = xv0, zf = xv1, zg = xv2, zo = xv3;
      #pragma unroll
      for (int w = 0; w < 4; ++w) {
        const float* zr = &z_s[s&1][w*528 + gb*33];
        zi += zr[uu]; zf += zr[8+uu]; zg += zr[16+uu]; zo += zr[24+uu];
      }
      const float ig = sigm(zi), fg = sigm(zf), og = sigm(zo);
      const float gg = tanh_f(zg);
      cst = fg*cst + ig*gg;
      const float hv = og * tanh_f(cst);
      const unsigned hvb = bf16bits(hv);
      const unsigned hnb = (unsigned)__shfl_down((int)hvb, 1);   // odd-u partner
      if (!(uu & 1)) {
        const unsigned sbit = (((unsigned)(s+1) >> 1) & 1u) ^ 1u;
        const unsigned d = ((hvb & ~1u) | sbit) | (hnb << 16);
        ast(&hw2p[(size_t)((((s+1)&1)*2 + dir)*16 + gb)*512 + (u0 >> 1) + (uu >> 1)], d);
      }
      outp[((size_t)gb*T_ + tin)*2048 + dir*U_ + u0 + uu] = hv*inv + add;
    }
    // no second barrier: z_s parity double-buffered
  }
}

extern "C" void kernel_launch(void* const* d_in, const int* in_sizes, int n_in,
                              void* d_out, int out_size, void* d_ws, size_t ws_size,
                              hipStream_t stream)
{
  const float* x  = (const float*)d_in[0];
  const float* kf = (const float*)d_in[1];
  const float* rf = (const float*)d_in[2];
  const float* bf = (const float*)d_in[3];
  const float* kb = (const float*)d_in[4];
  const float* rb = (const float*)d_in[5];
  const float* bb = (const float*)d_in[6];
  const float* ga = (const float*)d_in[7];
  const float* be = (const float*)d_in[8];
  const float* mm = (const float*)d_in[9];
  const float* mv = (const float*)d_in[10];
  float* outp = (float*)d_out;

  // ws: [hw2p packed 2par*2dir*16*512*4B = 256KB][xwf f16][xwb f16]
  unsigned* hw2p = (unsigned*)d_ws;
  __half* xwf    = (__half*)((char*)d_ws + 262144);
  __half* xwb    = xwf + (size_t)6400*G4_;

  // zero h buffer: memset-0 always fails the tag check (bit0=0 vs expected 1
  // at s=0), eliminating cross-replay stale-tag collisions for the 1-bit tag
  hipMemsetAsync(hw2p, 0, 262144, stream);
  gemm_xw<<<dim3(50, 32, 2), dim3(256), 0, stream>>>(x, kf, kb, bf, bb, xwf, xwb);
  lstm_rec<<<dim3(NBLK), dim3(256), 0, stream>>>(xwf, xwb, rf, rb, ga, be, mm, mv,
                                                 hw2p, outp);
}